// Round 3
// baseline (640.769 us; speedup 1.0000x reference)
//
#include <hip/hip_runtime.h>
#include <hip/hip_bf16.h>
#include <cstddef>

#define B_ 64
#define H_ 1024
#define L_ 400
#define V_ 50000
#define VP_ 50500   // V + OOV_PAD

typedef short short8 __attribute__((ext_vector_type(8)));
typedef float f32x4 __attribute__((ext_vector_type(4)));

static __device__ __forceinline__ short f2bf(float f) {
  unsigned u = __float_as_uint(f);
  u += 0x7fffu + ((u >> 16) & 1u);   // round-to-nearest-even
  return (short)(u >> 16);
}

// packed fp32->bf16 via v_cvt_pk_bf16_f32
static __device__ __forceinline__ short2 cvt2(float a, float b) {
  union { __hip_bfloat162 h; short2 s; } u;
  u.h = __float22bfloat162_rn(float2{a, b});
  return u.s;
}

static __device__ __forceinline__ short8 pack8(float4 a, float4 b) {
  short2 p0 = cvt2(a.x, a.y), p1 = cvt2(a.z, a.w);
  short2 p2 = cvt2(b.x, b.y), p3 = cvt2(b.z, b.w);
  short8 r;
  r[0] = p0.x; r[1] = p0.y; r[2] = p1.x; r[3] = p1.y;
  r[4] = p2.x; r[5] = p2.y; r[6] = p3.x; r[7] = p3.y;
  return r;
}

// ---------------- small GEMM: out[m=0..63][n] = sum_k X[m][k]*W[n][k] + bias[n]
// Block = 16 n-cols, 4 waves K-split 4-way, LDS cross-wave reduce.
// X fp32, split: k<1024 -> Xa (optional row gather via gidx), k>=1024 -> Xb.
// Two param sets selected by blockIdx.y. Blocks past N do aux work (zero A,
// copy hidden->hid_out) then exit.
__global__ __launch_bounds__(256) void k_gemm_small(
    const float* __restrict__ W0, const float* __restrict__ bias0,
    const float* __restrict__ Xa0, const float* __restrict__ Xb0,
    const int* __restrict__ gidx0, float* __restrict__ out0,
    int N0, int K0, int ldo0,
    const float* __restrict__ W1, const float* __restrict__ bias1,
    const float* __restrict__ Xa1, const float* __restrict__ Xb1,
    const int* __restrict__ gidx1, float* __restrict__ out1,
    int N1, int K1, int ldo1,
    const float* __restrict__ auxHid, float* __restrict__ auxA,
    float* __restrict__ auxHidOut) {
  const float* W    = blockIdx.y ? W1 : W0;
  const float* bias = blockIdx.y ? bias1 : bias0;
  const float* Xa   = blockIdx.y ? Xa1 : Xa0;
  const float* Xb   = blockIdx.y ? Xb1 : Xb0;
  const int* gidx   = blockIdx.y ? gidx1 : gidx0;
  float* out = blockIdx.y ? out1 : out0;
  int N   = blockIdx.y ? N1 : N0;
  int K   = blockIdx.y ? K1 : K0;
  int ldo = blockIdx.y ? ldo1 : ldo0;

  int tid = threadIdx.x, wave = tid >> 6, lane = tid & 63;
  int q = lane >> 4, nl = lane & 15;

  if ((int)blockIdx.x * 16 >= N) {           // aux / idle blocks
    if (auxA) {
      int bx = blockIdx.x - (N + 15) / 16;
      if (bx < 64) {
        int idx = bx * 256 + tid;            // float4 over 64*1024
        ((float4*)auxA)[idx] = make_float4(0.f, 0.f, 0.f, 0.f);
        ((float4*)auxHidOut)[idx] = ((const float4*)auxHid)[idx];
      }
    }
    return;
  }

  int n = blockIdx.x * 16 + nl;
  int nld = n < N ? n : (N - 1);
  int kpw = K >> 2;
  int kbeg = wave * kpw;
  const float* wr = W + (size_t)nld * K;

  int rid[4];
  #pragma unroll
  for (int mt = 0; mt < 4; ++mt) {
    int m = mt * 16 + nl;
    rid[mt] = gidx ? gidx[m] : m;
  }

  f32x4 acc[4];
  #pragma unroll
  for (int i = 0; i < 4; ++i) acc[i] = (f32x4){0.f, 0.f, 0.f, 0.f};

  for (int k0 = kbeg; k0 < kbeg + kpw; k0 += 32) {
    int kk = k0 + q * 8;                     // quads never straddle 1024
    float4 w0 = *(const float4*)(wr + kk);
    float4 w1 = *(const float4*)(wr + kk + 4);
    short8 bf = pack8(w0, w1);
    bool lo = kk < 1024;
    #pragma unroll
    for (int mt = 0; mt < 4; ++mt) {
      const float* xp = lo ? (Xa + (size_t)rid[mt] * H_ + kk)
                           : (Xb + (size_t)(mt * 16 + nl) * H_ + (kk - 1024));
      float4 x0 = *(const float4*)xp;
      float4 x1 = *(const float4*)(xp + 4);
      short8 af = pack8(x0, x1);
      acc[mt] = __builtin_amdgcn_mfma_f32_16x16x32_bf16(af, bf, acc[mt], 0, 0, 0);
    }
  }

  __shared__ float red[4][64][16];           // 16 KB
  #pragma unroll
  for (int mt = 0; mt < 4; ++mt)
    #pragma unroll
    for (int r = 0; r < 4; ++r)
      red[wave][mt * 16 + q * 4 + r][nl] = acc[mt][r];
  __syncthreads();
  for (int i = tid; i < 1024; i += 256) {
    int m = i >> 4, c = i & 15;
    int nn = blockIdx.x * 16 + c;
    if (nn < N) {
      float s = red[0][m][c] + red[1][m][c] + red[2][m][c] + red[3][m][c] + bias[nn];
      out[(size_t)m * ldo + nn] = s;
    }
  }
}

// ---------------- fused attention softmax + apply.
// grid (8 l-chunks of 50, 64 b). Each block recomputes the 400-wide softmax
// in LDS, applies its l-chunk, atomically accumulates into A.
__global__ __launch_bounds__(256) void k_attnsm(
    const float* __restrict__ S, const float* __restrict__ enc,
    float* __restrict__ aw_out, float* __restrict__ A) {
  __shared__ float w[L_];
  __shared__ float red[256];
  int lc = blockIdx.x, b = blockIdx.y, t = threadIdx.x;
  float a0 = S[b * L_ + t];
  float a1 = (t < L_ - 256) ? S[b * L_ + 256 + t] : -1e30f;
  float m = fmaxf(a0, a1);
  red[t] = m; __syncthreads();
  for (int s = 128; s > 0; s >>= 1) { if (t < s) red[t] = fmaxf(red[t], red[t + s]); __syncthreads(); }
  m = red[0]; __syncthreads();
  float e0 = __expf(a0 - m);
  float e1 = (t < L_ - 256) ? __expf(a1 - m) : 0.f;
  red[t] = e0 + e1; __syncthreads();
  for (int s = 128; s > 0; s >>= 1) { if (t < s) red[t] += red[t + s]; __syncthreads(); }
  float z = red[0];
  w[t] = e0 / z;
  if (t < L_ - 256) w[256 + t] = e1 / z;
  __syncthreads();
  if (lc == 0) {
    aw_out[b * L_ + t] = w[t];
    if (t < L_ - 256) aw_out[b * L_ + 256 + t] = w[256 + t];
  }
  float4 acc = make_float4(0.f, 0.f, 0.f, 0.f);
  for (int l = lc * 50; l < lc * 50 + 50; ++l) {
    float wg = w[l];
    float4 e = ((const float4*)(enc + ((size_t)l * B_ + b) * H_))[t];
    acc.x += wg * e.x; acc.y += wg * e.y; acc.z += wg * e.z; acc.w += wg * e.w;
  }
  float* dst = A + (size_t)b * H_ + t * 4;
  atomicAdd(dst + 0, acc.x); atomicAdd(dst + 1, acc.y);
  atomicAdd(dst + 2, acc.z); atomicAdd(dst + 3, acc.w);
}

// ---------------- GRU elementwise (writes h_new as bf16) + p_gen blocks
__global__ __launch_bounds__(256) void k_gru_gen(
    const float* __restrict__ gi, const float* __restrict__ gh,
    const float* __restrict__ hid, short* __restrict__ HNb,
    const float* __restrict__ C, const float* __restrict__ gW,
    const float* __restrict__ gb, float* __restrict__ PG) {
  __shared__ float red[256];
  int blk = blockIdx.x, t = threadIdx.x;
  if (blk < 256) {
    int idx = blk * 256 + t;                 // 65536
    int b = idx >> 10, h = idx & 1023;
    float ir = gi[b * 3072 + h], iz = gi[b * 3072 + 1024 + h], inn = gi[b * 3072 + 2048 + h];
    float hr = gh[b * 3072 + h], hz = gh[b * 3072 + 1024 + h], hn = gh[b * 3072 + 2048 + h];
    float r = 1.f / (1.f + __expf(-(ir + hr)));
    float z = 1.f / (1.f + __expf(-(iz + hz)));
    float n = tanhf(inn + r * hn);
    HNb[idx] = f2bf((1.f - z) * n + z * hid[idx]);
  } else {
    int b = blk - 256;
    float acc = 0.f;
    for (int k = t; k < 2 * H_; k += 256) {
      float x = (k < H_) ? C[b * H_ + k] : hid[b * H_ + k - H_];
      acc += x * gW[k];
    }
    red[t] = acc; __syncthreads();
    for (int s = 128; s > 0; s >>= 1) { if (t < s) red[t] += red[t + s]; __syncthreads(); }
    if (t == 0) PG[b] = 1.f / (1.f + __expf(-(red[0] + gb[0])));
  }
}

// ---------------- vocab GEMM: P[m][n] = sum_k HNb[m][k]*out_W[n][k] + out_b[n]
// No LDS, no barriers: A-fragments from L2-resident bf16 HNb, W streamed.
__global__ __launch_bounds__(256) void k_gemm_vocab(
    const short* __restrict__ Xb, const float* __restrict__ W,
    const float* __restrict__ bias, float* __restrict__ P) {
  int tid = threadIdx.x, wave = tid >> 6, lane = tid & 63;
  int q = lane >> 4, nl = lane & 15;
  int n = blockIdx.x * 64 + wave * 16 + nl;
  int nld = n < V_ ? n : (V_ - 1);
  const float* wr = W + (size_t)nld * H_;
  f32x4 acc[4];
  #pragma unroll
  for (int i = 0; i < 4; ++i) acc[i] = (f32x4){0.f, 0.f, 0.f, 0.f};

  for (int k0 = 0; k0 < H_; k0 += 32) {
    int kk = k0 + q * 8;
    float4 w0 = *(const float4*)(wr + kk);
    float4 w1 = *(const float4*)(wr + kk + 4);
    short8 bf = pack8(w0, w1);
    #pragma unroll
    for (int mt = 0; mt < 4; ++mt) {
      short8 af = *(const short8*)(Xb + (size_t)(mt * 16 + nl) * H_ + kk);
      acc[mt] = __builtin_amdgcn_mfma_f32_16x16x32_bf16(af, bf, acc[mt], 0, 0, 0);
    }
  }
  if (n < V_) {
    float bv = bias[n];
    #pragma unroll
    for (int mt = 0; mt < 4; ++mt)
      #pragma unroll
      for (int r = 0; r < 4; ++r)
        P[(size_t)(mt * 16 + q * 4 + r) * VP_ + n] = acc[mt][r] + bv;
  }
}

// ---------------- per-row-chunk max + sumexp (4 chunks per row, 256 blocks)
__global__ __launch_bounds__(256) void k_rowred2(const float* __restrict__ P,
                                                 float* __restrict__ MX,
                                                 float* __restrict__ SE) {
  __shared__ float red[256];
  int b = blockIdx.x >> 2, c = blockIdx.x & 3;
  int t = threadIdx.x;
  int v0 = c * 12500, v1 = v0 + 12500;
  float m = -1e30f;
  for (int v = v0 + t; v < v1; v += 256) m = fmaxf(m, P[(size_t)b * VP_ + v]);
  red[t] = m; __syncthreads();
  for (int s = 128; s > 0; s >>= 1) { if (t < s) red[t] = fmaxf(red[t], red[t + s]); __syncthreads(); }
  m = red[0]; __syncthreads();
  float sum = 0.f;
  for (int v = v0 + t; v < v1; v += 256) sum += __expf(P[(size_t)b * VP_ + v] - m);
  red[t] = sum; __syncthreads();
  for (int s = 128; s > 0; s >>= 1) { if (t < s) red[t] += red[t + s]; __syncthreads(); }
  if (t == 0) { MX[blockIdx.x] = m; SE[blockIdx.x] = red[0]; }
}

// ---------------- in-place: p_final[b][v] = p_gen*(logit - logZ) for v<V, 0 pad
__global__ void k_final(float* __restrict__ P, const float* __restrict__ pg,
                        const float* __restrict__ MX, const float* __restrict__ SE) {
  int b = blockIdx.y;
  float m0 = MX[b * 4], m1 = MX[b * 4 + 1], m2 = MX[b * 4 + 2], m3 = MX[b * 4 + 3];
  float M = fmaxf(fmaxf(m0, m1), fmaxf(m2, m3));
  float Z = SE[b * 4] * __expf(m0 - M) + SE[b * 4 + 1] * __expf(m1 - M)
          + SE[b * 4 + 2] * __expf(m2 - M) + SE[b * 4 + 3] * __expf(m3 - M);
  float lz = M + __logf(Z);
  float g = pg[b];
  int v0 = blockIdx.x * 1024 + threadIdx.x * 4;
  if (v0 >= VP_) return;
  float4* p = (float4*)(P + (size_t)b * VP_ + v0);
  if (v0 < V_) {                              // 50000 % 4 == 0: no mixed quad
    float4 x = *p;
    x.x = g * (x.x - lz); x.y = g * (x.y - lz);
    x.z = g * (x.z - lz); x.w = g * (x.w - lz);
    *p = x;
  } else {
    *p = make_float4(0.f, 0.f, 0.f, 0.f);
  }
}

// ---------------- pointer-copy scatter
__global__ void k_scatter(float* __restrict__ P, const float* __restrict__ aw,
                          const int* __restrict__ fi, const float* __restrict__ pg) {
  int b = blockIdx.x, t = threadIdx.x;
  if (t >= L_) return;
  float g = 1.f - pg[b];
  int v = fi[b * L_ + t];
  atomicAdd(P + (size_t)b * VP_ + v, g * aw[b * L_ + t]);
}

extern "C" void kernel_launch(void* const* d_in, const int* in_sizes, int n_in,
                              void* d_out, int out_size, void* d_ws, size_t ws_size,
                              hipStream_t stream) {
  const int*   ids    = (const int*)d_in[0];
  const float* hid    = (const float*)d_in[1];
  const float* enc    = (const float*)d_in[2];
  const int*   fi     = (const int*)d_in[3];
  const float* emb    = (const float*)d_in[4];
  const float* attn_W = (const float*)d_in[5];
  const float* attn_b = (const float*)d_in[6];
  const float* comb_W = (const float*)d_in[7];
  const float* comb_b = (const float*)d_in[8];
  const float* W_ih   = (const float*)d_in[9];
  const float* W_hh   = (const float*)d_in[10];
  const float* b_ih   = (const float*)d_in[11];
  const float* b_hh   = (const float*)d_in[12];
  const float* out_W  = (const float*)d_in[13];
  const float* out_b  = (const float*)d_in[14];
  const float* gen_W  = (const float*)d_in[15];
  const float* gen_b  = (const float*)d_in[16];

  float* outp    = (float*)d_out;
  float* P       = outp;                              // [64][50500]
  float* hid_out = outp + (size_t)B_ * VP_;           // [1][64][1024]
  float* aw_out  = hid_out + B_ * H_;                 // [64][400]

  float* ws = (float*)d_ws;
  float* A   = ws;                      // [64][1024] attn_applied (atomics)
  float* C   = A + B_ * H_;             // [64][1024] combined
  float* S   = C + B_ * H_;             // [64][400] attn logits
  float* GI  = S + B_ * L_;             // [64][3072]
  float* GH  = GI + B_ * 3 * H_;        // [64][3072]
  float* PG  = GH + B_ * 3 * H_;        // [64]
  float* MX  = PG + B_;                 // [256]
  float* SE  = MX + 256;                // [256]
  short* HNb = (short*)(SE + 256);      // [64][1024] bf16 h_new

  // L1: attn logits (y=0, 25 blocks; spare blocks zero A + copy hid_out)
  //     + GRU gh = hid @ W_hh^T (y=1, 192 blocks)
  k_gemm_small<<<dim3(192, 2), 256, 0, stream>>>(
      attn_W, attn_b, emb, hid, ids, S, L_, 2 * H_, L_,
      W_hh, b_hh, hid, hid, nullptr, GH, 3 * H_, H_, 3 * H_,
      hid, A, hid_out);
  // L2: softmax + attn apply -> A (+ aw_out)
  k_attnsm<<<dim3(8, 64), 256, 0, stream>>>(S, enc, aw_out, A);
  // L3: combined = [emb-gather, A] @ comb_W^T
  k_gemm_small<<<dim3(64, 1), 256, 0, stream>>>(
      comb_W, comb_b, emb, A, ids, C, H_, 2 * H_, H_,
      comb_W, comb_b, emb, A, ids, C, H_, 2 * H_, H_,
      nullptr, nullptr, nullptr);
  // L4: gi = C @ W_ih^T
  k_gemm_small<<<dim3(192, 1), 256, 0, stream>>>(
      W_ih, b_ih, C, C, nullptr, GI, 3 * H_, H_, 3 * H_,
      W_ih, b_ih, C, C, nullptr, GI, 3 * H_, H_, 3 * H_,
      nullptr, nullptr, nullptr);
  // L5: GRU elementwise (bf16 h_new) + p_gen
  k_gru_gen<<<320, 256, 0, stream>>>(GI, GH, hid, HNb, C, gen_W, gen_b, PG);
  // L6: vocab logits
  k_gemm_vocab<<<782, 256, 0, stream>>>(HNb, out_W, out_b, P);
  // L7: per-chunk max/sumexp
  k_rowred2<<<256, 256, 0, stream>>>(P, MX, SE);
  // L8: finalize log-softmax * p_gen, zero pad
  k_final<<<dim3(50, 64), 256, 0, stream>>>(P, PG, MX, SE);
  // L9: pointer-copy scatter
  k_scatter<<<64, 512, 0, stream>>>(P, aw_out, fi, PG);
}